// Round 3
// baseline (661.120 us; speedup 1.0000x reference)
//
#include <hip/hip_runtime.h>
#include <stdint.h>

#define NB 512
#define SL 1024
#define NT 64
#define BPB 16  // batches per block (MFMA N dimension)

typedef __attribute__((ext_vector_type(8))) short bf16x8;
typedef __attribute__((ext_vector_type(4))) float f32x4;
typedef __attribute__((ext_vector_type(4))) unsigned int u32x4;

// RNE round fp32 -> bf16 (as uint16 in low bits)
__device__ __forceinline__ uint32_t bf16_rne(float x) {
    uint32_t u = __float_as_uint(x);
    return (u + 0x7fffu + ((u >> 16) & 1u)) >> 16;
}
// f32 pair -> packed bf16 dword (src0 -> lo, src1 -> hi), RNE
__device__ __forceinline__ uint32_t cvtpk_bf16(float lo, float hi) {
    uint32_t r;
    asm("v_cvt_pk_bf16_f32 %0, %1, %2" : "=v"(r) : "v"(lo), "v"(hi));
    return r;
}
// gfx950 VALU cross-lane swaps (l <-> l^16 / l^32). Used only in
// direction-agnostic patterns (sum/max of the pair), so either hardware
// convention is correct.
__device__ __forceinline__ void plswap16_f(float& a, float& b) {
    asm("v_permlane16_swap_b32 %0, %1" : "+v"(a), "+v"(b));
}
__device__ __forceinline__ void plswap32_f(float& a, float& b) {
    asm("v_permlane32_swap_b32 %0, %1" : "+v"(a), "+v"(b));
}
__device__ __forceinline__ void plswap16_i(int& a, int& b) {
    asm("v_permlane16_swap_b32 %0, %1" : "+v"(a), "+v"(b));
}
__device__ __forceinline__ void plswap32_i(int& a, int& b) {
    asm("v_permlane32_swap_b32 %0, %1" : "+v"(a), "+v"(b));
}

__device__ __forceinline__ f32x4 mfma_bf16(const u32x4& a, const u32x4& b, const f32x4& c) {
    union U { u32x4 u; bf16x8 s; };
    U ua; ua.u = a;
    U ub; ub.u = b;
    return __builtin_amdgcn_mfma_f32_16x16x32_bf16(ua.s, ub.s, c, 0, 0, 0);
}

// One wave per 16 batches (lengths are globally sorted descending, so a
// block's batches have near-equal lengths). Forward scan in scaled-exp
// domain as a 64x64 x 64x16 GEMM per step on the matrix cores.
//
// Layouts (m89-verified D; standard A/B):
//   D tile T: lane l holds D[m = 16T + 4q + r][n = l&15], q = l>>4, r = 0..3.
//   B: lane l holds k = 8q + slot, col n = l&15.   A: row m = l&15, same k map.
// k-permutation trick: intra-lane slot->k order cancels between A and B, and
// we CHOOSE the k->tag map so that D's 16 f32 pack directly (cvt_pk of
// adjacent r) into the next step's B fragment with zero cross-lane movement.
// The constant A = exp(trans) is loaded pre-permuted to match:
//   B slot (q, kt, w, h) holds tag p = 16*(2kt + (w>>1)) + 4q + 2*(w&1) + h
//   A[m][k=8q+2w+h] = exp(trans[p][m])
__global__ void __launch_bounds__(64) crf_mfma_kernel(
    const int* __restrict__ tags, const void* __restrict__ mask,
    const float* __restrict__ emit, const float* __restrict__ trans,
    float* __restrict__ out)
{
    const int b0 = blockIdx.x * BPB;
    const int lane = threadIdx.x;
    const int q = lane >> 4;
    const int n = lane & 15;
    const int bb = b0 + n;

    const int* trow = tags + (size_t)bb * SL;
    const float* erow = emit + (size_t)bb * SL * NT;

    // ---------- phase 0: gold-path score + length (4 lanes per batch) ----------
    const unsigned char* mb = (const unsigned char*)mask;
    const bool m32 = ((mb[1] | mb[2] | mb[3]) == 0);  // dtype sniff

    float acc = 0.f;
    int cnt = 0;
    const int i0 = q * (SL / 4);
    #pragma unroll 8
    for (int jj = 0; jj < SL / 4; ++jj) {
        const int i = i0 + jj;
        const int mk = m32 ? (((const int*)mask)[(size_t)bb * SL + i] != 0)
                           : (mb[(size_t)bb * SL + i] != 0);
        const int tg = trow[i];
        float val = erow[(size_t)i * NT + tg];
        if (i > 0) val += trans[trow[i - 1] * NT + tg];
        acc += mk ? val : 0.f;
        cnt += mk;
    }
    {   // sum over the 4 q-lanes of this batch column (direction-agnostic)
        float pa = acc, pb = acc;
        plswap16_f(pa, pb); acc = pa + pb;
        pa = acc; pb = acc;
        plswap32_f(pa, pb); acc = pa + pb;
        int ca = cnt, cb = cnt;
        plswap16_i(ca, cb); cnt = ca + cb;
        ca = cnt; cb = cnt;
        plswap32_i(ca, cb); cnt = ca + cb;
    }
    const float tsn = acc;     // gold score of batch bb (all 4 q-lanes agree)
    const int fin = cnt - 1;   // finishing step index of batch bb
    const int lmax = __shfl(cnt, 0, 64);  // block max length (sorted desc)
    const int last = lmax - 1;

    // ---------- A fragments: pre-permuted exp(transition) ----------
    u32x4 Afr[4][2];
    #pragma unroll
    for (int T = 0; T < 4; ++T) {
        #pragma unroll
        for (int kt = 0; kt < 2; ++kt) {
            uint32_t wv[4];
            #pragma unroll
            for (int w = 0; w < 4; ++w) {
                const int p0 = 16 * (2 * kt + (w >> 1)) + 4 * q + 2 * (w & 1);
                const int m = 16 * T + n;
                const uint32_t lo = bf16_rne(__expf(trans[p0 * NT + m]));
                const uint32_t hi = bf16_rne(__expf(trans[(p0 + 1) * NT + m]));
                wv[w] = lo | (hi << 16);
            }
            Afr[T][kt].x = wv[0]; Afr[T][kt].y = wv[1];
            Afr[T][kt].z = wv[2]; Afr[T][kt].w = wv[3];
        }
    }

    // ---------- init state: d[T][r] = exp(emit[bb][0][16T+4q+r]) ----------
    const float* ep = erow + 4 * q;  // + i*NT + 16*T for tile T
    f32x4 d[4];
    #pragma unroll
    for (int T = 0; T < 4; ++T) {
        f32x4 e = *(const f32x4*)(ep + 16 * T);
        d[T].x = __expf(e.x); d[T].y = __expf(e.y);
        d[T].z = __expf(e.z); d[T].w = __expf(e.w);
    }
    float logacc = 0.f;

    // ---------- helpers ----------
    auto extractNow = [&](int icur) {
        // column logZ = logacc + log(sum over 64 tags of column n)
        f32x4 s4 = d[0] + d[1] + d[2] + d[3];
        float sl = (s4.x + s4.y) + (s4.z + s4.w);
        float pa = sl, pb = sl;
        plswap16_f(pa, pb); sl = pa + pb;
        pa = sl; pb = sl;
        plswap32_f(pa, pb); sl = pa + pb;
        if (q == 0 && fin == icur)
            out[bb] = -(tsn - (logacc + __logf(sl)));
    };

    auto step = [&](const f32x4 (&et)[4]) {
        f32x4 ex[4];
        #pragma unroll
        for (int T = 0; T < 4; ++T) {
            ex[T].x = __expf(et[T].x); ex[T].y = __expf(et[T].y);
            ex[T].z = __expf(et[T].z); ex[T].w = __expf(et[T].w);
        }
        u32x4 B0, B1;
        B0.x = cvtpk_bf16(d[0].x, d[0].y); B0.y = cvtpk_bf16(d[0].z, d[0].w);
        B0.z = cvtpk_bf16(d[1].x, d[1].y); B0.w = cvtpk_bf16(d[1].z, d[1].w);
        B1.x = cvtpk_bf16(d[2].x, d[2].y); B1.y = cvtpk_bf16(d[2].z, d[2].w);
        B1.z = cvtpk_bf16(d[3].x, d[3].y); B1.w = cvtpk_bf16(d[3].z, d[3].w);
        const f32x4 z = {0.f, 0.f, 0.f, 0.f};
        #pragma unroll
        for (int T = 0; T < 4; ++T) {
            f32x4 a = mfma_bf16(Afr[T][0], B0, z);
            a = mfma_bf16(Afr[T][1], B1, a);
            d[T] = a * ex[T];
        }
    };

    auto renorm = [&]() {
        // per-column power-of-2 rescale; representative = max over the 4
        // q-lanes' d[0].x (uniform across the column's lanes)
        float rep = d[0].x;
        float pa = rep, pb = rep;
        plswap16_f(pa, pb); rep = fmaxf(pa, pb);
        pa = rep; pb = rep;
        plswap32_f(pa, pb); rep = fmaxf(pa, pb);
        const uint32_t ub = __float_as_uint(rep);
        const int e = (int)((ub >> 23) & 255u);
        const float sc = __uint_as_float((uint32_t)(254 - e) << 23);  // 2^(127-e)
        #pragma unroll
        for (int T = 0; T < 4; ++T) d[T] *= sc;
        logacc += (float)(e - 127) * 0.69314718055994530942f;
    };

    auto loadGroup = [&](f32x4 (&buf)[4][4], int i) {
        #pragma unroll
        for (int s = 0; s < 4; ++s) {
            int r = i + s;
            r = r < last ? r : last;  // clamp: prefetch past end reads valid rows
            #pragma unroll
            for (int T = 0; T < 4; ++T)
                buf[s][T] = *(const f32x4*)(ep + (size_t)r * NT + 16 * T);
        }
    };

    auto doGroup = [&](const f32x4 (&buf)[4][4], int i) {
        const bool gate = (__ballot((fin >= i) && (fin <= i + 3)) != 0ULL);
        #pragma unroll
        for (int s = 0; s < 4; ++s) {
            step(buf[s]);
            if (gate) {
                if (__ballot(fin == i + s) != 0ULL) extractNow(i + s);
            }
        }
        renorm();
    };

    // ---------- scan ----------
    if (__ballot(fin == 0) != 0ULL) extractNow(0);  // len==1 batches

    int i = 1;
    if (last >= 1) {
        f32x4 eA[4][4], eB[4][4];
        if (i + 3 <= last) {
            loadGroup(eA, i);
            for (;;) {
                const bool more = (i + 7 <= last);
                if (more) loadGroup(eB, i + 4);
                doGroup(eA, i);
                i += 4;
                if (!more) break;
                const bool more2 = (i + 7 <= last);
                if (more2) loadGroup(eA, i + 4);
                doGroup(eB, i);
                i += 4;
                if (!more2) break;
            }
        }
        for (; i <= last; ++i) {  // remainder (<=3 steps)
            f32x4 er[4];
            #pragma unroll
            for (int T = 0; T < 4; ++T)
                er[T] = *(const f32x4*)(ep + (size_t)i * NT + 16 * T);
            step(er);
            if (__ballot(fin == i) != 0ULL) extractNow(i);
        }
    }
}

extern "C" void kernel_launch(void* const* d_in, const int* in_sizes, int n_in,
                              void* d_out, int out_size, void* d_ws, size_t ws_size,
                              hipStream_t stream) {
    (void)in_sizes; (void)n_in; (void)out_size; (void)d_ws; (void)ws_size;
    const int*   tags  = (const int*)d_in[0];
    const void*  mask  = d_in[1];
    const float* emit  = (const float*)d_in[2];
    const float* trans = (const float*)d_in[3];
    float* out = (float*)d_out;

    crf_mfma_kernel<<<dim3(NB / BPB), dim3(64), 0, stream>>>(tags, mask, emit, trans, out);
}